// Round 25
// baseline (131.642 us; speedup 1.0000x reference)
//
#include <hip/hip_runtime.h>

#define NXT 32640   // xlmr tokens
#define NS  16320   // stanza words
#define NE  65280   // edges
#define DD  768
#define GD  256
#define NLAB 5
#define CAP 32      // per-word edge capacity (Binomial mean 4; P(>=32) < 1e-20)

typedef __attribute__((ext_vector_type(8))) short bf16x8;
typedef __attribute__((ext_vector_type(8))) unsigned short u16x8;
typedef __attribute__((ext_vector_type(4))) float f32x4;
typedef __attribute__((ext_vector_type(8))) float f32x8;

__device__ inline unsigned short f2b(float f) {  // fp32 -> bf16 RNE
    unsigned int u = __float_as_uint(f);
    unsigned int r = (u + 0x7FFFu + ((u >> 16) & 1u)) >> 16;
    return (unsigned short)r;
}
__device__ inline float b2f(unsigned short h) {
    return __uint_as_float((unsigned int)h << 16);
}

// Tiled 64x64 transpose-convert (coalesced both sides)
__device__ inline void tile_transpose(const float* __restrict__ src, unsigned short* __restrict__ dst,
                                      int K, int k0, int n0, int tid) {
    __shared__ unsigned short tl[64][65];
#pragma unroll
    for (int i = 0; i < 16; ++i) {
        int idx = tid + i * 256;
        int r = idx >> 6, c = idx & 63;
        tl[r][c] = f2b(src[(size_t)(k0 + r) * GD + n0 + c]);
    }
    __syncthreads();
#pragma unroll
    for (int i = 0; i < 16; ++i) {
        int idx = tid + i * 256;
        int rr = idx >> 6, cc = idx & 63;
        dst[(size_t)(n0 + rr) * K + k0 + cc] = tl[cc][rr];
    }
}

// ---------------- setup: zero cnt + weight transposes + WclsT fp32 + posLogit ----------------
__global__ void k_setup(int* __restrict__ cnt,
                        const float* __restrict__ Wc, unsigned short* __restrict__ WcT,
                        const float* __restrict__ gcn_W, unsigned short* __restrict__ WT,
                        const float* __restrict__ Wcls, float* __restrict__ WclsT,
                        const float* __restrict__ upos_table, const float* __restrict__ bcls,
                        float* __restrict__ posLogit) {
    int b = blockIdx.x, t = threadIdx.x;
    if (b < 64) {
        int i = b * 256 + t;
        if (i < NS) cnt[i] = 0;
    } else if (b < 112) {
        int tile = b - 64;
        tile_transpose(Wc, WcT, DD, (tile >> 2) * 64, (tile & 3) * 64, t);
    } else if (b < 128) {
        int tile = b - 112;
        tile_transpose(gcn_W, WT, GD, (tile >> 2) * 64, (tile & 3) * 64, t);
    } else if (b < 144) {
        int tile = b - 128;
        tile_transpose(gcn_W + (size_t)GD * GD, WT + (size_t)GD * GD, GD,
                       (tile >> 2) * 64, (tile & 3) * 64, t);
    } else if (b < 159) {
        int idx = (b - 144) * 256 + t;          // 5*768 = 3840
        if (idx < NLAB * DD) {
            int l = idx / DD, k = idx - l * DD;
            WclsT[idx] = Wcls[(size_t)k * NLAB + l];
        }
    } else {
        if (t < 17 * NLAB) {
            int u = t / NLAB, l = t - u * NLAB;
            float a = bcls[l];
#pragma unroll
            for (int p = 0; p < 4; ++p) {
                float pv = upos_table[u * 4 + p];
                pv = pv > 0.f ? pv : 0.f;
                a += pv * Wcls[(size_t)(DD + GD + p) * NLAB + l];
            }
            posLogit[t] = a;
        }
    }
}

// ---------------- mega0 v7: BM=64 x BN=64 x BK=32, 256thr, 1020 blocks (4/CU co-resident) ----------------
// decode: xcd=b&7, seq=b>>3, bm64=xcd*32+(seq>>2), bn=seq&3 -> the 4 bn-blocks of a bm are consecutive
// in one XCD's dispatch order (L2 shares their x reads).
// thread: kc=tid&3 (4 lanes = 128B contiguous), rl=(tid>>2)&15, g=tid>>6 (= wave).
// LDS (16B chunks): A [0,256) = 4 row-granules x 64; B [256,512) = 4 col-granules x 64. 8 KB.
// fill blocks [1024,1279).
__global__ __launch_bounds__(256, 4) void k_mega0(const float* __restrict__ x,
                                                  const unsigned short* __restrict__ WcT,
                                                  const float* __restrict__ WclsT,
                                                  const float* __restrict__ bc,
                                                  const int* __restrict__ ei,
                                                  int* __restrict__ cnt, int* __restrict__ csr_src,
                                                  unsigned short* __restrict__ h_bf,
                                                  float* __restrict__ partial) {
    __shared__ unsigned short lds[512 * 8];   // 8 KB
    const int tid = threadIdx.x;
    if (blockIdx.x >= 1024) {                  // ---- fill part ----
        int e = (blockIdx.x - 1024) * 256 + tid;
        if (e < NE) {
            int dst = ei[NE + e];
            int slot = atomicAdd(&cnt[dst], 1);
            if (slot < CAP) csr_src[(size_t)dst * CAP + slot] = ei[e];
        }
        return;
    }
    const int xcd = blockIdx.x & 7, seq = blockIdx.x >> 3;
    const int bm64 = xcd * 32 + (seq >> 2);
    const int bn   = seq & 3;
    if (bm64 >= 255) return;                   // 4 invalid ids
    const int bm = bm64 * 64;

    const int lane = tid & 63;
    const int wv   = tid >> 6;                 // wave = 16-row group

    const int kc = tid & 3, rl = (tid >> 2) & 15, g = tid >> 6;
    const int w_loc = g * 16 + rl;
    const float* xr0 = x + (size_t)(2 * (bm + w_loc)) * DD + kc * 8;
    const float* xr1 = xr0 + DD;
    const int aw_slot = g * 64 + kc * 16 + rl;
    const float* wcl = WclsT + kc * 8;

    // B staging: 256 chunks, 1/thread: n=tid>>6, c=tid&63 (kq=c>>4, cl=c&15)
    const int bn_ = tid >> 6, c_ = tid & 63, kq = c_ >> 4, cl = c_ & 15;
    const unsigned short* srcB = WcT + (size_t)(bn * 64 + bn_ * 16 + cl) * DD + kq * 8;

    const bf16x8* ldsv = (const bf16x8*)lds;
    f32x4 acc[4] = {};
    float lg0[NLAB] = {}, lg1[NLAB] = {};

    // x double-buffer: preload iteration 0
    f32x8 va = *(const f32x8*)xr0;
    f32x8 vb = *(const f32x8*)xr1;

    for (int it = 0; it < 24; ++it) {
        const int k0 = it * 32;
        __builtin_amdgcn_global_load_lds(srcB + k0, lds + (size_t)(256 + tid) * 8, 16, 0, 0);
        u16x8 pool;
#pragma unroll
        for (int i = 0; i < 8; ++i) pool[i] = f2b((va[i] + vb[i]) * 0.5f);
        *(u16x8*)(lds + (size_t)aw_slot * 8) = pool;
        if (bn == 0) {
#pragma unroll
            for (int l = 0; l < NLAB; ++l) {
                f32x8 wv8 = *(const f32x8*)(wcl + (size_t)l * DD + k0);
#pragma unroll
                for (int i = 0; i < 8; ++i) {
                    float ra = va[i] > 0.f ? va[i] : 0.f;
                    float rb = vb[i] > 0.f ? vb[i] : 0.f;
                    lg0[l] += ra * wv8[i];
                    lg1[l] += rb * wv8[i];
                }
            }
        }
        // prefetch next iteration's x
        f32x8 va_n = va, vb_n = vb;
        if (it < 23) {
            va_n = *(const f32x8*)(xr0 + k0 + 32);
            vb_n = *(const f32x8*)(xr1 + k0 + 32);
        }
        __syncthreads();
        {
            bf16x8 a = ldsv[wv * 64 + lane];
#pragma unroll
            for (int n = 0; n < 4; ++n) {
                bf16x8 b = ldsv[256 + n * 64 + lane];
                acc[n] = __builtin_amdgcn_mfma_f32_16x16x32_bf16(a, b, acc[n], 0, 0, 0);
            }
        }
        __syncthreads();
        va = va_n; vb = vb_n;
    }

    const int rl2 = lane & 15, rq = lane >> 4;
    {
        int row0 = bm + wv * 16 + rq * 4;
#pragma unroll
        for (int n = 0; n < 4; ++n) {
            int col = bn * 64 + n * 16 + rl2;
            float bv = bc[col];
#pragma unroll
            for (int r = 0; r < 4; ++r)
                h_bf[(size_t)(row0 + r) * GD + col] = f2b(acc[n][r] + bv);
        }
    }

    // logits (bn==0): butterfly over kc (lane bits 0-1)
    if (bn == 0) {
#pragma unroll
        for (int l = 0; l < NLAB; ++l) {
            lg0[l] += __shfl_xor(lg0[l], 1); lg0[l] += __shfl_xor(lg0[l], 2);
            lg1[l] += __shfl_xor(lg1[l], 1); lg1[l] += __shfl_xor(lg1[l], 2);
        }
        if (kc == 0) {
            int w = bm + w_loc;
            float* pp = partial + (size_t)w * 2 * NLAB;
#pragma unroll
            for (int l = 0; l < NLAB; ++l) { pp[l] = lg0[l]; pp[NLAB + l] = lg1[l]; }
        }
    }
}

// ---------------- LDS-staged MFMA GEMM, BK=64 (layer GEMMs, K=256) ----------------
__global__ __launch_bounds__(256) void k_gemm(const unsigned short* __restrict__ A,
                                              const unsigned short* __restrict__ BT,
                                              const float* __restrict__ bias,
                                              unsigned short* __restrict__ out,
                                              int K, int nbn) {
    __shared__ unsigned short lds[1536 * 8];   // 24 KB
    const int tid  = threadIdx.x;
    const int lane = tid & 63;
    const int wv   = tid >> 6;
    const int wr   = wv >> 1, wc = wv & 1;
    const int bm   = (blockIdx.x / nbn) * 64;
    const int bn   = (blockIdx.x % nbn) * 128;

    const int g  = tid >> 6, w_ = tid & 63, kc = w_ >> 4, rl = w_ & 15;
    const unsigned short* srcA  = A  + (size_t)(bm + g * 16 + rl) * K + kc * 8;
    const unsigned short* srcB0 = BT + (size_t)(bn      + g * 16 + rl) * K + kc * 8;
    const unsigned short* srcB1 = BT + (size_t)(bn + 64 + g * 16 + rl) * K + kc * 8;

    unsigned short* dA0 = lds + (size_t)tid * 8;
    unsigned short* dA1 = dA0 + 256 * 8;
    unsigned short* dB  = lds + (size_t)(512 + tid) * 8;

    const bf16x8* fA = (const bf16x8*)lds + (wr * 2) * 64 + lane;
    const bf16x8* fB = (const bf16x8*)lds + 512 + wc * 256 + lane;

    f32x4 acc[2][4] = {};
    for (int k0 = 0; k0 < K; k0 += 64) {
        __builtin_amdgcn_global_load_lds(srcA  + k0,      dA0,            16, 0, 0);
        __builtin_amdgcn_global_load_lds(srcA  + k0 + 32, dA1,            16, 0, 0);
        __builtin_amdgcn_global_load_lds(srcB0 + k0,      dB,             16, 0, 0);
        __builtin_amdgcn_global_load_lds(srcB1 + k0,      dB + 256 * 8,   16, 0, 0);
        __builtin_amdgcn_global_load_lds(srcB0 + k0 + 32, dB + 512 * 8,   16, 0, 0);
        __builtin_amdgcn_global_load_lds(srcB1 + k0 + 32, dB + 768 * 8,   16, 0, 0);
        __syncthreads();
#pragma unroll
        for (int kh = 0; kh < 2; ++kh) {
            bf16x8 a0 = fA[kh * 256], a1 = fA[kh * 256 + 64];
            const bf16x8* fb = fB + kh * 512;
            bf16x8 b0 = fb[0], b1 = fb[64], b2 = fb[128], b3 = fb[192];
            acc[0][0] = __builtin_amdgcn_mfma_f32_16x16x32_bf16(a0, b0, acc[0][0], 0, 0, 0);
            acc[0][1] = __builtin_amdgcn_mfma_f32_16x16x32_bf16(a0, b1, acc[0][1], 0, 0, 0);
            acc[0][2] = __builtin_amdgcn_mfma_f32_16x16x32_bf16(a0, b2, acc[0][2], 0, 0, 0);
            acc[0][3] = __builtin_amdgcn_mfma_f32_16x16x32_bf16(a0, b3, acc[0][3], 0, 0, 0);
            acc[1][0] = __builtin_amdgcn_mfma_f32_16x16x32_bf16(a1, b0, acc[1][0], 0, 0, 0);
            acc[1][1] = __builtin_amdgcn_mfma_f32_16x16x32_bf16(a1, b1, acc[1][1], 0, 0, 0);
            acc[1][2] = __builtin_amdgcn_mfma_f32_16x16x32_bf16(a1, b2, acc[1][2], 0, 0, 0);
            acc[1][3] = __builtin_amdgcn_mfma_f32_16x16x32_bf16(a1, b3, acc[1][3], 0, 0, 0);
        }
        __syncthreads();
    }

    const int rl2 = lane & 15, rq = lane >> 4;
#pragma unroll
    for (int m = 0; m < 2; ++m) {
        int row0 = bm + wr * 32 + m * 16 + rq * 4;
#pragma unroll
        for (int n = 0; n < 4; ++n) {
            int col = bn + wc * 64 + n * 16 + rl2;
            float bv = bias ? bias[col] : 0.f;
#pragma unroll
            for (int r = 0; r < 4; ++r)
                out[(size_t)(row0 + r) * GD + col] = f2b(acc[m][n][r] + bv);
        }
    }
}

// ---------------- gather (layer 1) ----------------
__global__ void k_gather(const int* __restrict__ cnt, const int* __restrict__ csr_src,
                         const unsigned short* __restrict__ hW,
                         const float* __restrict__ b, unsigned short* __restrict__ hout) {
    int w    = blockIdx.x * 4 + (threadIdx.x >> 6);
    int lane = threadIdx.x & 63;
    int c = cnt[w];
    float dw = rsqrtf((float)c + 1.0f);
    const int* sl = csr_src + (size_t)w * CAP;
    float ax = 0.f, ay = 0.f, az = 0.f, aw = 0.f;
    for (int j = 0; j < c; ++j) {
        int src = sl[j];
        float cf = rsqrtf((float)cnt[src] + 1.0f) * dw;
        ushort4 v = *(const ushort4*)&hW[(size_t)src * GD + lane * 4];
        ax += cf * b2f(v.x); ay += cf * b2f(v.y); az += cf * b2f(v.z); aw += cf * b2f(v.w);
    }
    ushort4 sv = *(const ushort4*)&hW[(size_t)w * GD + lane * 4];
    f32x4 bv = *(const f32x4*)&b[lane * 4];
    float c2 = dw * dw;
    float rx = ax + b2f(sv.x) * c2 + bv[0];
    float ry = ay + b2f(sv.y) * c2 + bv[1];
    float rz = az + b2f(sv.z) * c2 + bv[2];
    float rw = aw + b2f(sv.w) * c2 + bv[3];
    ushort4 o;
    o.x = f2b(rx > 0.f ? rx : 0.f);
    o.y = f2b(ry > 0.f ? ry : 0.f);
    o.z = f2b(rz > 0.f ? rz : 0.f);
    o.w = f2b(rw > 0.f ? rw : 0.f);
    *(ushort4*)&hout[(size_t)w * GD + lane * 4] = o;
}

// ---------------- gather (layer 2) + classifier + log_softmax ----------------
__global__ void k_gather_final(const int* __restrict__ cnt, const int* __restrict__ csr_src,
                               const unsigned short* __restrict__ hW,
                               const float* __restrict__ b,
                               const float* __restrict__ partial,
                               const int* __restrict__ upos_ids,
                               const float* __restrict__ posLogit,
                               const float* __restrict__ Wcls,
                               float* __restrict__ out) {
    int w    = blockIdx.x * 4 + (threadIdx.x >> 6);
    int lane = threadIdx.x & 63;
    int c = cnt[w];
    float dw = rsqrtf((float)c + 1.0f);
    const int* sl = csr_src + (size_t)w * CAP;
    float ax = 0.f, ay = 0.f, az = 0.f, aw = 0.f;
    for (int j = 0; j < c; ++j) {
        int src = sl[j];
        float cf = rsqrtf((float)cnt[src] + 1.0f) * dw;
        ushort4 v = *(const ushort4*)&hW[(size_t)src * GD + lane * 4];
        ax += cf * b2f(v.x); ay += cf * b2f(v.y); az += cf * b2f(v.z); aw += cf * b2f(v.w);
    }
    ushort4 sv = *(const ushort4*)&hW[(size_t)w * GD + lane * 4];
    f32x4 bv = *(const f32x4*)&b[lane * 4];
    float c2 = dw * dw;
    float hv[4];
    hv[0] = ax + b2f(sv.x) * c2 + bv[0];
    hv[1] = ay + b2f(sv.y) * c2 + bv[1];
    hv[2] = az + b2f(sv.z) * c2 + bv[2];
    hv[3] = aw + b2f(sv.w) * c2 + bv[3];
    float acc[NLAB] = {};
#pragma unroll
    for (int i = 0; i < 4; ++i) {
        float v = hv[i] > 0.f ? hv[i] : 0.f;
        const float* wr = Wcls + (size_t)(DD + lane * 4 + i) * NLAB;
#pragma unroll
        for (int l = 0; l < NLAB; ++l) acc[l] += v * wr[l];
    }
#pragma unroll
    for (int off = 32; off > 0; off >>= 1)
#pragma unroll
        for (int l = 0; l < NLAB; ++l) acc[l] += __shfl_xor(acc[l], off);
    if (lane == 0) {
        const float* pl = posLogit + (size_t)upos_ids[w] * NLAB;  // bcls folded in
        const float* pp = partial + (size_t)w * 2 * NLAB;
#pragma unroll
        for (int t = 0; t < 2; ++t) {
            float lg[NLAB];
#pragma unroll
            for (int l = 0; l < NLAB; ++l) lg[l] = acc[l] + pp[t * NLAB + l] + pl[l];
            float m = lg[0];
#pragma unroll
            for (int l = 1; l < NLAB; ++l) m = fmaxf(m, lg[l]);
            float s = 0.f;
#pragma unroll
            for (int l = 0; l < NLAB; ++l) s += __expf(lg[l] - m);
            float lse = __logf(s) + m;
            float* op = out + (size_t)(2 * w + t) * NLAB;
#pragma unroll
            for (int l = 0; l < NLAB; ++l) op[l] = lg[l] - lse;
        }
    }
}

extern "C" void kernel_launch(void* const* d_in, const int* in_sizes, int n_in,
                              void* d_out, int out_size, void* d_ws, size_t ws_size,
                              hipStream_t stream) {
    const float* x          = (const float*)d_in[0];
    const int*   ei         = (const int*)d_in[2];
    const int*   upos_ids   = (const int*)d_in[3];
    const float* Wc         = (const float*)d_in[4];
    const float* bc         = (const float*)d_in[5];
    const float* gcn_W      = (const float*)d_in[6];
    const float* gcn_b      = (const float*)d_in[7];
    const float* upos_table = (const float*)d_in[8];
    const float* Wcls       = (const float*)d_in[9];
    const float* bcls       = (const float*)d_in[10];
    float* out = (float*)d_out;

    char* ws = (char*)d_ws;
    float* partial          = (float*)ws;            ws += (size_t)NXT * NLAB * 4;
    float* WclsT            = (float*)ws;            ws += (size_t)NLAB * DD * 4;
    float* posLogit         = (float*)ws;            ws += (size_t)17 * NLAB * 4;
    unsigned short* h_bf    = (unsigned short*)ws;   ws += (size_t)NS * GD * 2;
    unsigned short* hW_bf   = (unsigned short*)ws;   ws += (size_t)NS * GD * 2;
    unsigned short* WcT     = (unsigned short*)ws;   ws += (size_t)DD * GD * 2;
    unsigned short* WT      = (unsigned short*)ws;   ws += (size_t)2 * GD * GD * 2;
    int* cnt                = (int*)ws;              ws += (size_t)NS * 4;
    int* csr_src            = (int*)ws;              ws += (size_t)NS * CAP * 4;

    // 1: setup (zero cnt + weight transposes + WclsT + posLogit)
    k_setup<<<160, 256, 0, stream>>>(cnt, Wc, WcT, gcn_W, WT, Wcls, WclsT,
                                     upos_table, bcls, posLogit);
    // 2: mega0 v7 = BN=64 tiles, 4 blocks/CU co-resident, XCD-grouped ∪ {CSR fill}
    k_mega0<<<1279, 256, 0, stream>>>(x, WcT, WclsT, bc, ei, cnt, csr_src, h_bf, partial);
    // 3-4: layer 1
    k_gemm<<<(NS / 64) * 2, 256, 0, stream>>>(h_bf, WT, nullptr, hW_bf, GD, 2);
    k_gather<<<NS / 4, 256, 0, stream>>>(cnt, csr_src, hW_bf, gcn_b, h_bf);
    // 5-6: layer 2 with fused classifier + log_softmax
    k_gemm<<<(NS / 64) * 2, 256, 0, stream>>>(h_bf, WT + (size_t)GD * GD, nullptr, hW_bf, GD, 2);
    k_gather_final<<<NS / 4, 256, 0, stream>>>(cnt, csr_src, hW_bf, gcn_b + GD,
                                               partial, upos_ids, posLogit, Wcls, out);
}

// Round 26
// 111.329 us; speedup vs baseline: 1.1825x; 1.1825x over previous
//
#include <hip/hip_runtime.h>

#define NXT 32640   // xlmr tokens
#define NS  16320   // stanza words
#define NE  65280   // edges
#define DD  768
#define GD  256
#define NLAB 5
#define CAP 32      // per-word edge capacity (Binomial mean 4; P(>=32) < 1e-20)

typedef __attribute__((ext_vector_type(8))) short bf16x8;
typedef __attribute__((ext_vector_type(8))) unsigned short u16x8;
typedef __attribute__((ext_vector_type(4))) float f32x4;
typedef __attribute__((ext_vector_type(8))) float f32x8;

__device__ inline unsigned short f2b(float f) {  // fp32 -> bf16 RNE
    unsigned int u = __float_as_uint(f);
    unsigned int r = (u + 0x7FFFu + ((u >> 16) & 1u)) >> 16;
    return (unsigned short)r;
}
__device__ inline float b2f(unsigned short h) {
    return __uint_as_float((unsigned int)h << 16);
}
// involutive chunk swizzle: spreads A-pool writes across banks (R23: conflicts 2.7M -> 0.4M)
__device__ inline int swz(int c) { return c ^ ((c >> 4) & 7); }

// Tiled 64x64 transpose-convert (coalesced both sides)
__device__ inline void tile_transpose(const float* __restrict__ src, unsigned short* __restrict__ dst,
                                      int K, int k0, int n0, int tid) {
    __shared__ unsigned short tl[64][65];
#pragma unroll
    for (int i = 0; i < 16; ++i) {
        int idx = tid + i * 256;
        int r = idx >> 6, c = idx & 63;
        tl[r][c] = f2b(src[(size_t)(k0 + r) * GD + n0 + c]);
    }
    __syncthreads();
#pragma unroll
    for (int i = 0; i < 16; ++i) {
        int idx = tid + i * 256;
        int rr = idx >> 6, cc = idx & 63;
        dst[(size_t)(n0 + rr) * K + k0 + cc] = tl[cc][rr];
    }
}

// ---------------- setup: zero cnt + weight transposes + WclsT fp32 + posLogit ----------------
__global__ void k_setup(int* __restrict__ cnt,
                        const float* __restrict__ Wc, unsigned short* __restrict__ WcT,
                        const float* __restrict__ gcn_W, unsigned short* __restrict__ WT,
                        const float* __restrict__ Wcls, float* __restrict__ WclsT,
                        const float* __restrict__ upos_table, const float* __restrict__ bcls,
                        float* __restrict__ posLogit) {
    int b = blockIdx.x, t = threadIdx.x;
    if (b < 64) {
        int i = b * 256 + t;
        if (i < NS) cnt[i] = 0;
    } else if (b < 112) {
        int tile = b - 64;
        tile_transpose(Wc, WcT, DD, (tile >> 2) * 64, (tile & 3) * 64, t);
    } else if (b < 128) {
        int tile = b - 112;
        tile_transpose(gcn_W, WT, GD, (tile >> 2) * 64, (tile & 3) * 64, t);
    } else if (b < 144) {
        int tile = b - 128;
        tile_transpose(gcn_W + (size_t)GD * GD, WT + (size_t)GD * GD, GD,
                       (tile >> 2) * 64, (tile & 3) * 64, t);
    } else if (b < 159) {
        int idx = (b - 144) * 256 + t;          // 5*768 = 3840
        if (idx < NLAB * DD) {
            int l = idx / DD, k = idx - l * DD;
            WclsT[idx] = Wcls[(size_t)k * NLAB + l];
        }
    } else {
        if (t < 17 * NLAB) {
            int u = t / NLAB, l = t - u * NLAB;
            float a = bcls[l];
#pragma unroll
            for (int p = 0; p < 4; ++p) {
                float pv = upos_table[u * 4 + p];
                pv = pv > 0.f ? pv : 0.f;
                a += pv * Wcls[(size_t)(DD + GD + p) * NLAB + l];
            }
            posLogit[t] = a;
        }
    }
}

// ---------------- mega0 v5p (R24 best): v5s + x register double-buffer ----------------
__global__ __launch_bounds__(512, 2) void k_mega0(const float* __restrict__ x,
                                                  const unsigned short* __restrict__ WcT,
                                                  const float* __restrict__ WclsT,
                                                  const float* __restrict__ bc,
                                                  const int* __restrict__ ei,
                                                  int* __restrict__ cnt, int* __restrict__ csr_src,
                                                  unsigned short* __restrict__ h_bf,
                                                  float* __restrict__ partial) {
    __shared__ unsigned short lds[1536 * 8];   // 24 KB
    const int tid = threadIdx.x;
    if (blockIdx.x >= 512) {                   // ---- fill part ----
        int e = (blockIdx.x - 512) * 512 + tid;
        if (e < NE) {
            int dst = ei[NE + e];
            int slot = atomicAdd(&cnt[dst], 1);
            if (slot < CAP) csr_src[(size_t)dst * CAP + slot] = ei[e];
        }
        return;
    }
    const int xcd = blockIdx.x & 7, slot = blockIdx.x >> 3;
    const int bm64 = (slot >> 1) * 8 + xcd;
    const int bn   = slot & 1;
    if (bm64 >= 255) return;
    const int bm = bm64 * 64;

    const int lane = tid & 63;
    const int wv   = tid >> 6;
    const int wr   = wv & 3, wc = wv >> 2;

    const int kc = tid & 7, rl = (tid >> 3) & 15, g = tid >> 7;
    const int w_loc = g * 16 + rl;
    const float* xr0 = x + (size_t)(2 * (bm + w_loc)) * DD + kc * 8;
    const float* xr1 = xr0 + DD;
    const int aw_slot = swz((kc >> 2) * 256 + g * 64 + (kc & 3) * 16 + rl);
    const float* wcl = WclsT + kc * 8;

    const unsigned short* srcB[2];
#pragma unroll
    for (int q = 0; q < 2; ++q) {
        int s = q * 512 + tid;
        int gran = s >> 8, chunk = s & 255;
        int nh = gran >> 1, kh = gran & 1;
        int rg = chunk >> 6, kc2 = (chunk >> 4) & 3, rl2 = chunk & 15;
        srcB[q] = WcT + (size_t)(bn * 128 + nh * 64 + rg * 16 + rl2) * DD + kh * 32 + kc2 * 8;
    }

    const bf16x8* ldsv = (const bf16x8*)lds;
    f32x4 acc[4] = {};
    float lg0[NLAB] = {}, lg1[NLAB] = {};

    // x double-buffer: preload iteration 0
    f32x8 va = *(const f32x8*)xr0;
    f32x8 vb = *(const f32x8*)xr1;

    for (int it = 0; it < 12; ++it) {
        const int k0 = it * 64;
#pragma unroll
        for (int q = 0; q < 2; ++q)
            __builtin_amdgcn_global_load_lds(srcB[q] + k0, lds + (size_t)(512 + q * 512 + tid) * 8, 16, 0, 0);
        u16x8 pool;
#pragma unroll
        for (int i = 0; i < 8; ++i) pool[i] = f2b((va[i] + vb[i]) * 0.5f);
        *(u16x8*)(lds + (size_t)aw_slot * 8) = pool;
        if (bn == 0) {
#pragma unroll
            for (int l = 0; l < NLAB; ++l) {
                f32x8 wv8 = *(const f32x8*)(wcl + (size_t)l * DD + k0);
#pragma unroll
                for (int i = 0; i < 8; ++i) {
                    float ra = va[i] > 0.f ? va[i] : 0.f;
                    float rb = vb[i] > 0.f ? vb[i] : 0.f;
                    lg0[l] += ra * wv8[i];
                    lg1[l] += rb * wv8[i];
                }
            }
        }
        // prefetch next iteration's x: latency co-pays with the gl_lds drain at the barrier
        f32x8 va_n = va, vb_n = vb;
        if (it < 11) {
            va_n = *(const f32x8*)(xr0 + k0 + 64);
            vb_n = *(const f32x8*)(xr1 + k0 + 64);
        }
        __syncthreads();
#pragma unroll
        for (int kh = 0; kh < 2; ++kh) {
            bf16x8 a = ldsv[swz(kh * 256 + wr * 64 + lane)];
#pragma unroll
            for (int n = 0; n < 4; ++n) {
                bf16x8 b = ldsv[512 + (wc * 2 + kh) * 256 + n * 64 + lane];
                acc[n] = __builtin_amdgcn_mfma_f32_16x16x32_bf16(a, b, acc[n], 0, 0, 0);
            }
        }
        __syncthreads();
        va = va_n; vb = vb_n;
    }

    const int rl2 = lane & 15, rq = lane >> 4;
    {
        int row0 = bm + wr * 16 + rq * 4;
#pragma unroll
        for (int n = 0; n < 4; ++n) {
            int col = bn * 128 + wc * 64 + n * 16 + rl2;
            float bv = bc[col];
#pragma unroll
            for (int r = 0; r < 4; ++r)
                h_bf[(size_t)(row0 + r) * GD + col] = f2b(acc[n][r] + bv);
        }
    }

    if (bn == 0) {
#pragma unroll
        for (int l = 0; l < NLAB; ++l) {
            lg0[l] += __shfl_xor(lg0[l], 1); lg0[l] += __shfl_xor(lg0[l], 2); lg0[l] += __shfl_xor(lg0[l], 4);
            lg1[l] += __shfl_xor(lg1[l], 1); lg1[l] += __shfl_xor(lg1[l], 2); lg1[l] += __shfl_xor(lg1[l], 4);
        }
        if (kc == 0) {
            int w = bm + w_loc;
            float* pp = partial + (size_t)w * 2 * NLAB;
#pragma unroll
            for (int l = 0; l < NLAB; ++l) { pp[l] = lg0[l]; pp[NLAB + l] = lg1[l]; }
        }
    }
}

// ---------------- LDS-staged MFMA GEMM, BK=64 (layer GEMMs, K=256) ----------------
__global__ __launch_bounds__(256) void k_gemm(const unsigned short* __restrict__ A,
                                              const unsigned short* __restrict__ BT,
                                              const float* __restrict__ bias,
                                              unsigned short* __restrict__ out,
                                              int K, int nbn) {
    __shared__ unsigned short lds[1536 * 8];   // 24 KB
    const int tid  = threadIdx.x;
    const int lane = tid & 63;
    const int wv   = tid >> 6;
    const int wr   = wv >> 1, wc = wv & 1;
    const int bm   = (blockIdx.x / nbn) * 64;
    const int bn   = (blockIdx.x % nbn) * 128;

    const int g  = tid >> 6, w_ = tid & 63, kc = w_ >> 4, rl = w_ & 15;
    const unsigned short* srcA  = A  + (size_t)(bm + g * 16 + rl) * K + kc * 8;
    const unsigned short* srcB0 = BT + (size_t)(bn      + g * 16 + rl) * K + kc * 8;
    const unsigned short* srcB1 = BT + (size_t)(bn + 64 + g * 16 + rl) * K + kc * 8;

    unsigned short* dA0 = lds + (size_t)tid * 8;
    unsigned short* dA1 = dA0 + 256 * 8;
    unsigned short* dB  = lds + (size_t)(512 + tid) * 8;

    const bf16x8* fA = (const bf16x8*)lds + (wr * 2) * 64 + lane;
    const bf16x8* fB = (const bf16x8*)lds + 512 + wc * 256 + lane;

    f32x4 acc[2][4] = {};
    for (int k0 = 0; k0 < K; k0 += 64) {
        __builtin_amdgcn_global_load_lds(srcA  + k0,      dA0,            16, 0, 0);
        __builtin_amdgcn_global_load_lds(srcA  + k0 + 32, dA1,            16, 0, 0);
        __builtin_amdgcn_global_load_lds(srcB0 + k0,      dB,             16, 0, 0);
        __builtin_amdgcn_global_load_lds(srcB1 + k0,      dB + 256 * 8,   16, 0, 0);
        __builtin_amdgcn_global_load_lds(srcB0 + k0 + 32, dB + 512 * 8,   16, 0, 0);
        __builtin_amdgcn_global_load_lds(srcB1 + k0 + 32, dB + 768 * 8,   16, 0, 0);
        __syncthreads();
#pragma unroll
        for (int kh = 0; kh < 2; ++kh) {
            bf16x8 a0 = fA[kh * 256], a1 = fA[kh * 256 + 64];
            const bf16x8* fb = fB + kh * 512;
            bf16x8 b0 = fb[0], b1 = fb[64], b2 = fb[128], b3 = fb[192];
            acc[0][0] = __builtin_amdgcn_mfma_f32_16x16x32_bf16(a0, b0, acc[0][0], 0, 0, 0);
            acc[0][1] = __builtin_amdgcn_mfma_f32_16x16x32_bf16(a0, b1, acc[0][1], 0, 0, 0);
            acc[0][2] = __builtin_amdgcn_mfma_f32_16x16x32_bf16(a0, b2, acc[0][2], 0, 0, 0);
            acc[0][3] = __builtin_amdgcn_mfma_f32_16x16x32_bf16(a0, b3, acc[0][3], 0, 0, 0);
            acc[1][0] = __builtin_amdgcn_mfma_f32_16x16x32_bf16(a1, b0, acc[1][0], 0, 0, 0);
            acc[1][1] = __builtin_amdgcn_mfma_f32_16x16x32_bf16(a1, b1, acc[1][1], 0, 0, 0);
            acc[1][2] = __builtin_amdgcn_mfma_f32_16x16x32_bf16(a1, b2, acc[1][2], 0, 0, 0);
            acc[1][3] = __builtin_amdgcn_mfma_f32_16x16x32_bf16(a1, b3, acc[1][3], 0, 0, 0);
        }
        __syncthreads();
    }

    const int rl2 = lane & 15, rq = lane >> 4;
#pragma unroll
    for (int m = 0; m < 2; ++m) {
        int row0 = bm + wr * 32 + m * 16 + rq * 4;
#pragma unroll
        for (int n = 0; n < 4; ++n) {
            int col = bn + wc * 64 + n * 16 + rl2;
            float bv = bias ? bias[col] : 0.f;
#pragma unroll
            for (int r = 0; r < 4; ++r)
                out[(size_t)(row0 + r) * GD + col] = f2b(acc[m][n][r] + bv);
        }
    }
}

// ---------------- gather (layer 1) ----------------
__global__ void k_gather(const int* __restrict__ cnt, const int* __restrict__ csr_src,
                         const unsigned short* __restrict__ hW,
                         const float* __restrict__ b, unsigned short* __restrict__ hout) {
    int w    = blockIdx.x * 4 + (threadIdx.x >> 6);
    int lane = threadIdx.x & 63;
    int c = cnt[w];
    float dw = rsqrtf((float)c + 1.0f);
    const int* sl = csr_src + (size_t)w * CAP;
    float ax = 0.f, ay = 0.f, az = 0.f, aw = 0.f;
    for (int j = 0; j < c; ++j) {
        int src = sl[j];
        float cf = rsqrtf((float)cnt[src] + 1.0f) * dw;
        ushort4 v = *(const ushort4*)&hW[(size_t)src * GD + lane * 4];
        ax += cf * b2f(v.x); ay += cf * b2f(v.y); az += cf * b2f(v.z); aw += cf * b2f(v.w);
    }
    ushort4 sv = *(const ushort4*)&hW[(size_t)w * GD + lane * 4];
    f32x4 bv = *(const f32x4*)&b[lane * 4];
    float c2 = dw * dw;
    float rx = ax + b2f(sv.x) * c2 + bv[0];
    float ry = ay + b2f(sv.y) * c2 + bv[1];
    float rz = az + b2f(sv.z) * c2 + bv[2];
    float rw = aw + b2f(sv.w) * c2 + bv[3];
    ushort4 o;
    o.x = f2b(rx > 0.f ? rx : 0.f);
    o.y = f2b(ry > 0.f ? ry : 0.f);
    o.z = f2b(rz > 0.f ? rz : 0.f);
    o.w = f2b(rw > 0.f ? rw : 0.f);
    *(ushort4*)&hout[(size_t)w * GD + lane * 4] = o;
}

// ---------------- gather (layer 2) + classifier + log_softmax ----------------
__global__ void k_gather_final(const int* __restrict__ cnt, const int* __restrict__ csr_src,
                               const unsigned short* __restrict__ hW,
                               const float* __restrict__ b,
                               const float* __restrict__ partial,
                               const int* __restrict__ upos_ids,
                               const float* __restrict__ posLogit,
                               const float* __restrict__ Wcls,
                               float* __restrict__ out) {
    int w    = blockIdx.x * 4 + (threadIdx.x >> 6);
    int lane = threadIdx.x & 63;
    int c = cnt[w];
    float dw = rsqrtf((float)c + 1.0f);
    const int* sl = csr_src + (size_t)w * CAP;
    float ax = 0.f, ay = 0.f, az = 0.f, aw = 0.f;
    for (int j = 0; j < c; ++j) {
        int src = sl[j];
        float cf = rsqrtf((float)cnt[src] + 1.0f) * dw;
        ushort4 v = *(const ushort4*)&hW[(size_t)src * GD + lane * 4];
        ax += cf * b2f(v.x); ay += cf * b2f(v.y); az += cf * b2f(v.z); aw += cf * b2f(v.w);
    }
    ushort4 sv = *(const ushort4*)&hW[(size_t)w * GD + lane * 4];
    f32x4 bv = *(const f32x4*)&b[lane * 4];
    float c2 = dw * dw;
    float hv[4];
    hv[0] = ax + b2f(sv.x) * c2 + bv[0];
    hv[1] = ay + b2f(sv.y) * c2 + bv[1];
    hv[2] = az + b2f(sv.z) * c2 + bv[2];
    hv[3] = aw + b2f(sv.w) * c2 + bv[3];
    float acc[NLAB] = {};
#pragma unroll
    for (int i = 0; i < 4; ++i) {
        float v = hv[i] > 0.f ? hv[i] : 0.f;
        const float* wr = Wcls + (size_t)(DD + lane * 4 + i) * NLAB;
#pragma unroll
        for (int l = 0; l < NLAB; ++l) acc[l] += v * wr[l];
    }
#pragma unroll
    for (int off = 32; off > 0; off >>= 1)
#pragma unroll
        for (int l = 0; l < NLAB; ++l) acc[l] += __shfl_xor(acc[l], off);
    if (lane == 0) {
        const float* pl = posLogit + (size_t)upos_ids[w] * NLAB;  // bcls folded in
        const float* pp = partial + (size_t)w * 2 * NLAB;
#pragma unroll
        for (int t = 0; t < 2; ++t) {
            float lg[NLAB];
#pragma unroll
            for (int l = 0; l < NLAB; ++l) lg[l] = acc[l] + pp[t * NLAB + l] + pl[l];
            float m = lg[0];
#pragma unroll
            for (int l = 1; l < NLAB; ++l) m = fmaxf(m, lg[l]);
            float s = 0.f;
#pragma unroll
            for (int l = 0; l < NLAB; ++l) s += __expf(lg[l] - m);
            float lse = __logf(s) + m;
            float* op = out + (size_t)(2 * w + t) * NLAB;
#pragma unroll
            for (int l = 0; l < NLAB; ++l) op[l] = lg[l] - lse;
        }
    }
}

extern "C" void kernel_launch(void* const* d_in, const int* in_sizes, int n_in,
                              void* d_out, int out_size, void* d_ws, size_t ws_size,
                              hipStream_t stream) {
    const float* x          = (const float*)d_in[0];
    const int*   ei         = (const int*)d_in[2];
    const int*   upos_ids   = (const int*)d_in[3];
    const float* Wc         = (const float*)d_in[4];
    const float* bc         = (const float*)d_in[5];
    const float* gcn_W      = (const float*)d_in[6];
    const float* gcn_b      = (const float*)d_in[7];
    const float* upos_table = (const float*)d_in[8];
    const float* Wcls       = (const float*)d_in[9];
    const float* bcls       = (const float*)d_in[10];
    float* out = (float*)d_out;

    char* ws = (char*)d_ws;
    float* partial          = (float*)ws;            ws += (size_t)NXT * NLAB * 4;
    float* WclsT            = (float*)ws;            ws += (size_t)NLAB * DD * 4;
    float* posLogit         = (float*)ws;            ws += (size_t)17 * NLAB * 4;
    unsigned short* h_bf    = (unsigned short*)ws;   ws += (size_t)NS * GD * 2;
    unsigned short* hW_bf   = (unsigned short*)ws;   ws += (size_t)NS * GD * 2;
    unsigned short* WcT     = (unsigned short*)ws;   ws += (size_t)DD * GD * 2;
    unsigned short* WT      = (unsigned short*)ws;   ws += (size_t)2 * GD * GD * 2;
    int* cnt                = (int*)ws;              ws += (size_t)NS * 4;
    int* csr_src            = (int*)ws;              ws += (size_t)NS * CAP * 4;

    // 1: setup (zero cnt + weight transposes + WclsT + posLogit)
    k_setup<<<160, 256, 0, stream>>>(cnt, Wc, WcT, gcn_W, WT, Wcls, WclsT,
                                     upos_table, bcls, posLogit);
    // 2: mega0 v5p = v5s + x register double-buffer ∪ {CSR fill}
    k_mega0<<<640, 512, 0, stream>>>(x, WcT, WclsT, bc, ei, cnt, csr_src, h_bf, partial);
    // 3-4: layer 1
    k_gemm<<<(NS / 64) * 2, 256, 0, stream>>>(h_bf, WT, nullptr, hW_bf, GD, 2);
    k_gather<<<NS / 4, 256, 0, stream>>>(cnt, csr_src, hW_bf, gcn_b, h_bf);
    // 5-6: layer 2 with fused classifier + log_softmax
    k_gemm<<<(NS / 64) * 2, 256, 0, stream>>>(h_bf, WT + (size_t)GD * GD, nullptr, hW_bf, GD, 2);
    k_gather_final<<<NS / 4, 256, 0, stream>>>(cnt, csr_src, hW_bf, gcn_b + GD,
                                               partial, upos_ids, posLogit, Wcls, out);
}